// Round 3
// baseline (127.551 us; speedup 1.0000x reference)
//
#include <hip/hip_runtime.h>

#define B 4096
#define S 200
#define EMB_DIM 128
#define HIDDEN 256
#define NUM_CLASSES 20
#define VOCAB 100000
#define RB 4               // batch rows per block
#define JD 2               // 16-position chunks in flight per row per round

typedef __attribute__((ext_vector_type(8))) unsigned short ushort8;

// RNE float -> bf16 (inputs are finite, no NaN handling needed)
__device__ __forceinline__ unsigned short f2bf(float f) {
    unsigned u = __float_as_uint(f);
    unsigned r = u + 0x7fffu + ((u >> 16) & 1u);
    return (unsigned short)(r >> 16);
}

// ---------------------------------------------------------------------------
// Pass 1: stream-convert the fp32 table (51.2 MB, cold in HBM because the
// harness's 256 MiB ws re-poison flushes L3 every iteration) into a 25.6 MB
// bf16 table in d_ws. At its 76.8 MB streaming roofline (~13 us) -- fixed.
// ---------------------------------------------------------------------------
__global__ __launch_bounds__(256) void convert_kernel(
    const float* __restrict__ emb,          // [VOCAB*EMB_DIM]
    unsigned short* __restrict__ embh)      // [VOCAB*EMB_DIM] bf16 bits
{
    const long i = ((long)blockIdx.x * 256 + threadIdx.x) * 8;
    const float4 a = *(const float4*)(emb + i);
    const float4 b = *(const float4*)(emb + i + 4);
    ushort8 o;
    o[0] = f2bf(a.x); o[1] = f2bf(a.y); o[2] = f2bf(a.z); o[3] = f2bf(a.w);
    o[4] = f2bf(b.x); o[5] = f2bf(b.y); o[6] = f2bf(b.z); o[7] = f2bf(b.w);
    *(ushort8*)(embh + i) = o;
}

// ---------------------------------------------------------------------------
// Pass 2: fused gather + mean-pool + MLP, RB=4 rows/block (1024 blocks, 256
// threads). g = t>>4 (16 position groups), d = t&15 (16B slot of a 256B row).
//
// R2 post-mortem: gather is MIXED latency/L3-BW bound (-36% rounds / +28%
// traffic netted ~0). This version keeps 8 loads in flight (4 rows x JD=2
// chunks) but guards every chunk-load with a block-uniform scalar branch
// (chunk < nC[r], readfirstlane -> s_cbranch): short rows stop issuing when
// done. Gather traffic drops to the 16-granular useful set (113 MB, -36%)
// at an unchanged chip-wide round count; RB=4 halves W1 L2 traffic to 134 MB.
// ---------------------------------------------------------------------------
__global__ __launch_bounds__(256) void fused_kernel(
    const int* __restrict__ x,              // [B, S]
    const int* __restrict__ lens,           // [B]
    const unsigned short* __restrict__ embh,// [VOCAB, EMB_DIM] bf16
    const float* __restrict__ W1,           // [EMB_DIM, HIDDEN]
    const float* __restrict__ b1,           // [HIDDEN]
    const float* __restrict__ W2,           // [HIDDEN, NUM_CLASSES]
    const float* __restrict__ b2,           // [NUM_CLASSES]
    float* __restrict__ out)                // [B, NUM_CLASSES]
{
    __shared__ int   sidx[RB][256];              // 4 KB
    __shared__ float tmp[2][16][16][8];          // 16 KB (2 rows per pass)
    __shared__ float P[RB][EMB_DIM];             // 2 KB
    __shared__ float H[RB][HIDDEN];              // 4 KB
    __shared__ float part[RB][2][NUM_CLASSES];   // 640 B

    const int t  = threadIdx.x;
    const int b0 = blockIdx.x * RB;

    int Ls[RB];
    #pragma unroll
    for (int r = 0; r < RB; ++r) {
        Ls[r] = lens[b0 + r];
        int v = 0;
        if (t < Ls[r]) v = x[(long)(b0 + r) * S + t];   // L <= 199 < 256
        sidx[r][t] = v;                                  // zeros beyond L
    }
    __syncthreads();

    const int g   = t >> 4;    // position-in-chunk 0..15
    const int d   = t & 15;    // 16B slot within the 256B bf16 row
    const int dof = d << 3;    // element offset of the slot

    // Block-uniform chunk counts, forced to SGPR so guards are s_cbranch.
    int nC[RB];
    int nR = 1;
    #pragma unroll
    for (int r = 0; r < RB; ++r) {
        nC[r] = __builtin_amdgcn_readfirstlane((Ls[r] + 15) >> 4);   // 1..13
        const int rr = (nC[r] + JD - 1) / JD;                        // 1..7
        nR = rr > nR ? rr : nR;
    }

    float acc[RB][8];
    #pragma unroll
    for (int r = 0; r < RB; ++r)
        #pragma unroll
        for (int f = 0; f < 8; ++f) acc[r][f] = 0.f;

    int cur[RB][JD], nxt[RB][JD];
    #pragma unroll
    for (int r = 0; r < RB; ++r)
        #pragma unroll
        for (int j = 0; j < JD; ++j) cur[r][j] = sidx[r][(j << 4) + g];

    for (int it = 0; it < nR; ++it) {
        uint4 v[RB][JD];
        #pragma unroll
        for (int r = 0; r < RB; ++r)
            #pragma unroll
            for (int j = 0; j < JD; ++j)
                if (it * JD + j < nC[r])   // uniform -> scalar branch
                    v[r][j] = *(const uint4*)(embh + ((cur[r][j] << 7) + dof));

        // prefetch next round's indices before the vmcnt wait
        // (max chunk = 15 -> sidx index <= 255, always in bounds)
        #pragma unroll
        for (int r = 0; r < RB; ++r)
            #pragma unroll
            for (int j = 0; j < JD; ++j)
                nxt[r][j] = sidx[r][(((it + 1) * JD + j) << 4) + g];

        #pragma unroll
        for (int r = 0; r < RB; ++r)
            #pragma unroll
            for (int j = 0; j < JD; ++j)
                if (it * JD + j < nC[r]) {
                    const unsigned c0 = v[r][j].x, c1 = v[r][j].y;
                    const unsigned c2 = v[r][j].z, c3 = v[r][j].w;
                    acc[r][0] += __uint_as_float(c0 << 16);
                    acc[r][1] += __uint_as_float(c0 & 0xffff0000u);
                    acc[r][2] += __uint_as_float(c1 << 16);
                    acc[r][3] += __uint_as_float(c1 & 0xffff0000u);
                    acc[r][4] += __uint_as_float(c2 << 16);
                    acc[r][5] += __uint_as_float(c2 & 0xffff0000u);
                    acc[r][6] += __uint_as_float(c3 << 16);
                    acc[r][7] += __uint_as_float(c3 & 0xffff0000u);
                }

        #pragma unroll
        for (int r = 0; r < RB; ++r)
            #pragma unroll
            for (int j = 0; j < JD; ++j) cur[r][j] = nxt[r][j];
    }

    // Reduce 2 rows per pass through the 16 KB tmp buffer.
    #pragma unroll
    for (int half = 0; half < 2; ++half) {
        if (half) __syncthreads();           // pass-0 reads done before rewrite
        #pragma unroll
        for (int rr = 0; rr < 2; ++rr)
            #pragma unroll
            for (int f = 0; f < 8; ++f)
                tmp[rr][g][d][f] = acc[half * 2 + rr][f];
        __syncthreads();
        {
            const int rr  = t >> 7;          // 0..1
            const int dim = t & 127;
            float s = 0.f;
            #pragma unroll
            for (int gg = 0; gg < 16; ++gg) s += tmp[rr][gg][dim >> 3][dim & 7];
            const float L = rr ? (float)Ls[half * 2 + 1] : (float)Ls[half * 2];
            P[half * 2 + rr][dim] = s / L;   // static acc/Ls indexing only
        }
    }
    __syncthreads();

    // Layer 1: hidden unit t for all 4 rows; W1 element read once per block.
    {
        float hA[RB], hB[RB];
        #pragma unroll
        for (int r = 0; r < RB; ++r) { hA[r] = 0.f; hB[r] = 0.f; }
        for (int k = 0; k < EMB_DIM; k += 2) {
            const float wa = W1[(k)     * HIDDEN + t];
            const float wb = W1[(k + 1) * HIDDEN + t];
            #pragma unroll
            for (int r = 0; r < RB; ++r) {
                hA[r] = fmaf(P[r][k],     wa, hA[r]);
                hB[r] = fmaf(P[r][k + 1], wb, hB[r]);
            }
        }
        const float bb = b1[t];
        #pragma unroll
        for (int r = 0; r < RB; ++r)
            H[r][t] = fmaxf(hA[r] + hB[r] + bb, 0.f);
    }
    __syncthreads();

    // Layer 2: RB rows x 2 k-segments x 20 classes = 160 threads, 128-FMA.
    if (t < RB * 2 * NUM_CLASSES) {
        const int r  = t / (2 * NUM_CLASSES);
        const int u  = t - r * 2 * NUM_CLASSES;
        const int j  = u / NUM_CLASSES;
        const int c  = u - j * NUM_CLASSES;
        const int k0 = j * 128;
        float a0 = 0.f, a1 = 0.f;
        for (int k = k0; k < k0 + 128; k += 2) {
            a0 = fmaf(H[r][k],     W2[(k)     * NUM_CLASSES + c], a0);
            a1 = fmaf(H[r][k + 1], W2[(k + 1) * NUM_CLASSES + c], a1);
        }
        part[r][j][c] = a0 + a1;
    }
    __syncthreads();

    if (t < RB * NUM_CLASSES) {
        const int r = t / NUM_CLASSES;
        const int c = t - r * NUM_CLASSES;
        out[(long)(b0 + r) * NUM_CLASSES + c] =
            b2[c] + part[r][0][c] + part[r][1][c];
    }
}

extern "C" void kernel_launch(void* const* d_in, const int* in_sizes, int n_in,
                              void* d_out, int out_size, void* d_ws, size_t ws_size,
                              hipStream_t stream) {
    const int*   x    = (const int*)d_in[0];
    const int*   lens = (const int*)d_in[1];
    const float* emb  = (const float*)d_in[2];
    const float* W1   = (const float*)d_in[3];
    const float* b1   = (const float*)d_in[4];
    const float* W2   = (const float*)d_in[5];
    const float* b2   = (const float*)d_in[6];
    float*       out  = (float*)d_out;

    unsigned short* embh = (unsigned short*)d_ws;   // 25.6 MB bf16 table

    // VOCAB*EMB_DIM = 12.8M elems / 8 per thread / 256 per block = 6250 blocks
    convert_kernel<<<(VOCAB * EMB_DIM) / (8 * 256), 256, 0, stream>>>(emb, embh);
    fused_kernel<<<B / RB, 256, 0, stream>>>(x, lens, embh, W1, b1, W2, b2, out);
}

// Round 4
// 124.962 us; speedup vs baseline: 1.0207x; 1.0207x over previous
//
#include <hip/hip_runtime.h>

#define B 4096
#define S 200
#define EMB_DIM 128
#define HIDDEN 256
#define NUM_CLASSES 20
#define VOCAB 100000
#define RB 4               // batch rows per block, gathered as 2 pairs

typedef __attribute__((ext_vector_type(8))) unsigned short ushort8;

// RNE float -> bf16 (inputs are finite, no NaN handling needed)
__device__ __forceinline__ unsigned short f2bf(float f) {
    unsigned u = __float_as_uint(f);
    unsigned r = u + 0x7fffu + ((u >> 16) & 1u);
    return (unsigned short)(r >> 16);
}

// ---------------------------------------------------------------------------
// Pass 1: stream-convert the fp32 table (51.2 MB, cold in HBM because the
// harness's 256 MiB ws re-poison flushes L3 every iteration) into a 25.6 MB
// bf16 table in d_ws. At its 76.8 MB streaming roofline (~12.5 us) -- fixed.
// ---------------------------------------------------------------------------
__global__ __launch_bounds__(256) void convert_kernel(
    const float* __restrict__ emb,          // [VOCAB*EMB_DIM]
    unsigned short* __restrict__ embh)      // [VOCAB*EMB_DIM] bf16 bits
{
    const long i = ((long)blockIdx.x * 256 + threadIdx.x) * 8;
    const float4 a = *(const float4*)(emb + i);
    const float4 b = *(const float4*)(emb + i + 4);
    ushort8 o;
    o[0] = f2bf(a.x); o[1] = f2bf(a.y); o[2] = f2bf(a.z); o[3] = f2bf(a.w);
    o[4] = f2bf(b.x); o[5] = f2bf(b.y); o[6] = f2bf(b.z); o[7] = f2bf(b.w);
    *(ushort8*)(embh + i) = o;
}

// ---------------------------------------------------------------------------
// Pass 2: fused gather + mean-pool + MLP, RB=4 rows/block (1024 blocks, 256
// threads), rows gathered two-at-a-time with the R2-proven UNGUARDED pipeline.
//
// R3 post-mortem: padding reads go to vocab row 0 (sidx zeros) -> L1-hot,
// nearly free. Real gather traffic is ~105 MB no matter the granularity, so
// guard-based traffic cuts are worthless and their branch structure breaks
// the 8-load batch (R3 regression). The real reducible term is W1: 131 KB
// re-read per block. This version keeps R2's exact gather shape per pair
// (8 flat loads in flight, 64-pos rounds, branch-free) and halves block
// count -> W1 L2 traffic 268 -> 134 MB, single fully-resident generation.
// ---------------------------------------------------------------------------
__global__ __launch_bounds__(256, 4) void fused_kernel(
    const int* __restrict__ x,              // [B, S]
    const int* __restrict__ lens,           // [B]
    const unsigned short* __restrict__ embh,// [VOCAB, EMB_DIM] bf16
    const float* __restrict__ W1,           // [EMB_DIM, HIDDEN]
    const float* __restrict__ b1,           // [HIDDEN]
    const float* __restrict__ W2,           // [HIDDEN, NUM_CLASSES]
    const float* __restrict__ b2,           // [NUM_CLASSES]
    float* __restrict__ out)                // [B, NUM_CLASSES]
{
    __shared__ int   sidx[RB][256];              // 4 KB
    __shared__ float tmp[2][16][16][8];          // 16 KB (2 rows per pass)
    __shared__ float P[RB][EMB_DIM];             // 2 KB
    __shared__ float H[RB][HIDDEN];              // 4 KB
    __shared__ float part[RB][2][NUM_CLASSES];   // 640 B

    const int t  = threadIdx.x;
    const int b0 = blockIdx.x * RB;

    int Ls[RB];
    #pragma unroll
    for (int r = 0; r < RB; ++r) {
        Ls[r] = lens[b0 + r];
        int v = 0;
        if (t < Ls[r]) v = x[(long)(b0 + r) * S + t];   // L <= 199 < 256
        sidx[r][t] = v;                                  // zeros beyond L
    }
    __syncthreads();

    const int g   = t >> 4;    // position group 0..15
    const int d   = t & 15;    // 16B slot within the 256B bf16 row
    const int dof = d << 3;    // element offset of the slot

    float acc[RB][8];
    #pragma unroll
    for (int r = 0; r < RB; ++r)
        #pragma unroll
        for (int f = 0; f < 8; ++f) acc[r][f] = 0.f;

    // Two pair-phases, each identical to the R2 gather: 8 loads in flight,
    // no guards; the shorter row of a pair pads with row-0 (L1-hot) reads.
    #pragma unroll
    for (int pair = 0; pair < 2; ++pair) {
        const int na   = (Ls[pair * 2]     + 63) >> 6;   // 1..4
        const int nb   = (Ls[pair * 2 + 1] + 63) >> 6;   // 1..4
        const int nMax = na > nb ? na : nb;              // block-uniform

        int cur[2][4], nxt[2][4];
        #pragma unroll
        for (int p = 0; p < 2; ++p)
            #pragma unroll
            for (int j = 0; j < 4; ++j)
                cur[p][j] = sidx[pair * 2 + p][g + 16 * j];

        for (int it = 0; it < nMax; ++it) {
            uint4 v[2][4];
            #pragma unroll
            for (int p = 0; p < 2; ++p)
                #pragma unroll
                for (int j = 0; j < 4; ++j)
                    v[p][j] = *(const uint4*)(embh + ((cur[p][j] << 7) + dof));

            // prefetch next round's indices before the vmcnt wait
            // (wrap keeps the LDS read in-bounds; values unused on last round)
            const int nb2 = ((it + 1) & 3) << 6;
            #pragma unroll
            for (int p = 0; p < 2; ++p)
                #pragma unroll
                for (int j = 0; j < 4; ++j)
                    nxt[p][j] = sidx[pair * 2 + p][nb2 + g + 16 * j];

            #pragma unroll
            for (int p = 0; p < 2; ++p)
                #pragma unroll
                for (int j = 0; j < 4; ++j) {
                    const unsigned c0 = v[p][j].x, c1 = v[p][j].y;
                    const unsigned c2 = v[p][j].z, c3 = v[p][j].w;
                    acc[pair * 2 + p][0] += __uint_as_float(c0 << 16);
                    acc[pair * 2 + p][1] += __uint_as_float(c0 & 0xffff0000u);
                    acc[pair * 2 + p][2] += __uint_as_float(c1 << 16);
                    acc[pair * 2 + p][3] += __uint_as_float(c1 & 0xffff0000u);
                    acc[pair * 2 + p][4] += __uint_as_float(c2 << 16);
                    acc[pair * 2 + p][5] += __uint_as_float(c2 & 0xffff0000u);
                    acc[pair * 2 + p][6] += __uint_as_float(c3 << 16);
                    acc[pair * 2 + p][7] += __uint_as_float(c3 & 0xffff0000u);
                }

            #pragma unroll
            for (int p = 0; p < 2; ++p)
                #pragma unroll
                for (int j = 0; j < 4; ++j) cur[p][j] = nxt[p][j];
        }
    }

    // Reduce 2 rows per pass through the 16 KB tmp buffer (R3-proven).
    #pragma unroll
    for (int half = 0; half < 2; ++half) {
        if (half) __syncthreads();           // pass-0 reads done before rewrite
        #pragma unroll
        for (int rr = 0; rr < 2; ++rr)
            #pragma unroll
            for (int f = 0; f < 8; ++f)
                tmp[rr][g][d][f] = acc[half * 2 + rr][f];
        __syncthreads();
        {
            const int rr  = t >> 7;          // 0..1
            const int dim = t & 127;
            float s = 0.f;
            #pragma unroll
            for (int gg = 0; gg < 16; ++gg) s += tmp[rr][gg][dim >> 3][dim & 7];
            const float L = rr ? (float)Ls[half * 2 + 1] : (float)Ls[half * 2];
            P[half * 2 + rr][dim] = s / L;   // static acc/Ls indexing only
        }
    }
    __syncthreads();

    // Layer 1: hidden unit t for all 4 rows; W1 element read once per block.
    {
        float hA[RB], hB[RB];
        #pragma unroll
        for (int r = 0; r < RB; ++r) { hA[r] = 0.f; hB[r] = 0.f; }
        for (int k = 0; k < EMB_DIM; k += 2) {
            const float wa = W1[(k)     * HIDDEN + t];
            const float wb = W1[(k + 1) * HIDDEN + t];
            #pragma unroll
            for (int r = 0; r < RB; ++r) {
                hA[r] = fmaf(P[r][k],     wa, hA[r]);
                hB[r] = fmaf(P[r][k + 1], wb, hB[r]);
            }
        }
        const float bb = b1[t];
        #pragma unroll
        for (int r = 0; r < RB; ++r)
            H[r][t] = fmaxf(hA[r] + hB[r] + bb, 0.f);
    }
    __syncthreads();

    // Layer 2: RB rows x 2 k-segments x 20 classes = 160 threads, 128-FMA.
    if (t < RB * 2 * NUM_CLASSES) {
        const int r  = t / (2 * NUM_CLASSES);
        const int u  = t - r * 2 * NUM_CLASSES;
        const int j  = u / NUM_CLASSES;
        const int c  = u - j * NUM_CLASSES;
        const int k0 = j * 128;
        float a0 = 0.f, a1 = 0.f;
        for (int k = k0; k < k0 + 128; k += 2) {
            a0 = fmaf(H[r][k],     W2[(k)     * NUM_CLASSES + c], a0);
            a1 = fmaf(H[r][k + 1], W2[(k + 1) * NUM_CLASSES + c], a1);
        }
        part[r][j][c] = a0 + a1;
    }
    __syncthreads();

    if (t < RB * NUM_CLASSES) {
        const int r = t / NUM_CLASSES;
        const int c = t - r * NUM_CLASSES;
        out[(long)(b0 + r) * NUM_CLASSES + c] =
            b2[c] + part[r][0][c] + part[r][1][c];
    }
}

extern "C" void kernel_launch(void* const* d_in, const int* in_sizes, int n_in,
                              void* d_out, int out_size, void* d_ws, size_t ws_size,
                              hipStream_t stream) {
    const int*   x    = (const int*)d_in[0];
    const int*   lens = (const int*)d_in[1];
    const float* emb  = (const float*)d_in[2];
    const float* W1   = (const float*)d_in[3];
    const float* b1   = (const float*)d_in[4];
    const float* W2   = (const float*)d_in[5];
    const float* b2   = (const float*)d_in[6];
    float*       out  = (float*)d_out;

    unsigned short* embh = (unsigned short*)d_ws;   // 25.6 MB bf16 table

    // VOCAB*EMB_DIM = 12.8M elems / 8 per thread / 256 per block = 6250 blocks
    convert_kernel<<<(VOCAB * EMB_DIM) / (8 * 256), 256, 0, stream>>>(emb, embh);
    fused_kernel<<<B / RB, 256, 0, stream>>>(x, lens, embh, W1, b1, W2, b2, out);
}

// Round 5
// 123.080 us; speedup vs baseline: 1.0363x; 1.0153x over previous
//
#include <hip/hip_runtime.h>

#define B 4096
#define S 200
#define EMB_DIM 128
#define HIDDEN 256
#define NUM_CLASSES 20
#define VOCAB 100000
#define RB 4               // batch rows per block, gathered as 2 pairs

// ---------------------------------------------------------------------------
// Pass 1: fp32 table -> int8 with per-row scale. 51.2 MB read + 13.2 MB
// written = 64 MB streamed (~10.3 us). Each 32-lane group owns one 128-elem
// row: float4/thread, shfl_xor abs-max reduce, q = rn(v * 127/max),
// scale = max/127. Row 0 is all-zero -> scale 0, q 0 (padding stays exact).
// Error per element is ABSOLUTE-bounded at rowmax/255 (~2.3e-4) -- ~8x less
// than fp8 e4m3 at the same byte count for this N(0,0.02) data.
// ---------------------------------------------------------------------------
__global__ __launch_bounds__(256) void convert_q8(
    const float* __restrict__ emb,          // [VOCAB*EMB_DIM]
    signed char* __restrict__ qt,           // [VOCAB*EMB_DIM] int8
    float* __restrict__ scl)                // [VOCAB] per-row scale
{
    const int  t    = threadIdx.x;
    const long base = (long)blockIdx.x * 1024 + t * 4;   // element index
    const float4 v  = *(const float4*)(emb + base);

    float m = fmaxf(fmaxf(fabsf(v.x), fabsf(v.y)),
                    fmaxf(fabsf(v.z), fabsf(v.w)));
    #pragma unroll
    for (int off = 1; off < 32; off <<= 1)               // 32-lane row group
        m = fmaxf(m, __shfl_xor(m, off, 64));

    const float inv = m > 0.f ? 127.f / m : 0.f;
    const int q0 = __float2int_rn(v.x * inv);
    const int q1 = __float2int_rn(v.y * inv);
    const int q2 = __float2int_rn(v.z * inv);
    const int q3 = __float2int_rn(v.w * inv);
    const unsigned pk = (q0 & 255) | ((q1 & 255) << 8)
                      | ((q2 & 255) << 16) | ((q3 & 255) << 24);
    *(unsigned*)(qt + base) = pk;

    if ((t & 31) == 0) scl[base >> 7] = m * (1.f / 127.f);
}

// ---------------------------------------------------------------------------
// Pass 2: fused gather + mean-pool + MLP. R0-R4 post-mortem: five structural
// variants all land at 125 +/- 2.5 us -> the gather is BYTE-bound on the
// random L2-miss/L3 path; round counts, guards, and W1 traffic are invisible.
// So this version halves the gathered bytes: 128 B int8 rows + 4 B scale.
// Same proven pipeline shape as R4: 2 row-pairs, 8 unguarded loads in flight
// (4 x uint4 data + 4 x dword scale), 64 positions/row/round, padding -> row
// 0 (scale 0, exact). d = t&7 (16B slot = 16 dims), g = t>>3 (32 pos groups).
// Dequant fused into accumulate: acc = fmaf(scale, (float)q, acc).
// ---------------------------------------------------------------------------
__global__ __launch_bounds__(256) void fused_kernel(
    const int* __restrict__ x,              // [B, S]
    const int* __restrict__ lens,           // [B]
    const signed char* __restrict__ qt,     // [VOCAB, EMB_DIM] int8
    const float* __restrict__ scl,          // [VOCAB]
    const float* __restrict__ W1,           // [EMB_DIM, HIDDEN]
    const float* __restrict__ b1,           // [HIDDEN]
    const float* __restrict__ W2,           // [HIDDEN, NUM_CLASSES]
    const float* __restrict__ b2,           // [NUM_CLASSES]
    float* __restrict__ out)                // [B, NUM_CLASSES]
{
    __shared__ int   sidx[RB][256];              // 4 KB
    __shared__ float tmp[32][8][16];             // 16 KB (one row per pass)
    __shared__ float P[RB][EMB_DIM];             // 2 KB
    __shared__ float H[RB][HIDDEN];              // 4 KB
    __shared__ float part[RB][2][NUM_CLASSES];   // 640 B

    const int t  = threadIdx.x;
    const int b0 = blockIdx.x * RB;

    int Ls[RB];
    #pragma unroll
    for (int r = 0; r < RB; ++r) {
        Ls[r] = lens[b0 + r];
        int v = 0;
        if (t < Ls[r]) v = x[(long)(b0 + r) * S + t];   // L <= 199 < 256
        sidx[r][t] = v;                                  // zeros beyond L
    }
    __syncthreads();

    const int g   = t >> 3;    // position group 0..31
    const int d   = t & 7;     // 16B slot (16 dims) of the 128B int8 row
    const int dof = d << 4;    // byte offset of the slot

    #pragma unroll
    for (int pair = 0; pair < 2; ++pair) {
        const int na   = (Ls[pair * 2]     + 63) >> 6;   // 1..4
        const int nb   = (Ls[pair * 2 + 1] + 63) >> 6;   // 1..4
        const int nMax = na > nb ? na : nb;              // block-uniform

        float acc[2][16];
        #pragma unroll
        for (int p = 0; p < 2; ++p)
            #pragma unroll
            for (int f = 0; f < 16; ++f) acc[p][f] = 0.f;

        int cur[2][2], nxt[2][2];
        #pragma unroll
        for (int p = 0; p < 2; ++p)
            #pragma unroll
            for (int j = 0; j < 2; ++j)
                cur[p][j] = sidx[pair * 2 + p][(j << 5) + g];

        for (int it = 0; it < nMax; ++it) {
            uint4 v[2][2];
            float s[2][2];
            #pragma unroll
            for (int p = 0; p < 2; ++p)
                #pragma unroll
                for (int j = 0; j < 2; ++j) {
                    v[p][j] = *(const uint4*)(qt + ((cur[p][j] << 7) + dof));
                    s[p][j] = scl[cur[p][j]];
                }

            // prefetch next round's indices before the vmcnt wait
            // (wrap keeps the LDS read in-bounds; values unused on last round)
            const int nb2 = ((it + 1) & 3) << 6;
            #pragma unroll
            for (int p = 0; p < 2; ++p)
                #pragma unroll
                for (int j = 0; j < 2; ++j)
                    nxt[p][j] = sidx[pair * 2 + p][nb2 + (j << 5) + g];

            #pragma unroll
            for (int p = 0; p < 2; ++p)
                #pragma unroll
                for (int j = 0; j < 2; ++j) {
                    const float sc = s[p][j];
                    #pragma unroll
                    for (int w = 0; w < 4; ++w) {
                        const unsigned c = w == 0 ? v[p][j].x : w == 1 ? v[p][j].y
                                         : w == 2 ? v[p][j].z : v[p][j].w;
                        acc[p][w * 4 + 0] = fmaf(sc, (float)((int)(c << 24) >> 24), acc[p][w * 4 + 0]);
                        acc[p][w * 4 + 1] = fmaf(sc, (float)((int)(c << 16) >> 24), acc[p][w * 4 + 1]);
                        acc[p][w * 4 + 2] = fmaf(sc, (float)((int)(c <<  8) >> 24), acc[p][w * 4 + 2]);
                        acc[p][w * 4 + 3] = fmaf(sc, (float)((int)(c      ) >> 24), acc[p][w * 4 + 3]);
                    }
                }

            #pragma unroll
            for (int p = 0; p < 2; ++p)
                #pragma unroll
                for (int j = 0; j < 2; ++j) cur[p][j] = nxt[p][j];
        }

        // Reduce one row per pass through the 16 KB tmp buffer.
        #pragma unroll
        for (int rr = 0; rr < 2; ++rr) {
            if (pair || rr) __syncthreads();   // previous pass's reads done
            #pragma unroll
            for (int f = 0; f < 16; ++f)
                tmp[g][d][f] = acc[rr][f];
            __syncthreads();
            if (t < 128) {
                // dim t = slot(t>>4)*16 + (t&15); lanes hit distinct banks
                float ssum = 0.f;
                #pragma unroll
                for (int gg = 0; gg < 32; ++gg)
                    ssum += tmp[gg][t >> 4][t & 15];
                P[pair * 2 + rr][t] = ssum / (float)Ls[pair * 2 + rr];
            }
        }
    }
    __syncthreads();

    // Layer 1: hidden unit t for all 4 rows; W1 element read once per block.
    {
        float hA[RB], hB[RB];
        #pragma unroll
        for (int r = 0; r < RB; ++r) { hA[r] = 0.f; hB[r] = 0.f; }
        for (int k = 0; k < EMB_DIM; k += 2) {
            const float wa = W1[(k)     * HIDDEN + t];
            const float wb = W1[(k + 1) * HIDDEN + t];
            #pragma unroll
            for (int r = 0; r < RB; ++r) {
                hA[r] = fmaf(P[r][k],     wa, hA[r]);
                hB[r] = fmaf(P[r][k + 1], wb, hB[r]);
            }
        }
        const float bb = b1[t];
        #pragma unroll
        for (int r = 0; r < RB; ++r)
            H[r][t] = fmaxf(hA[r] + hB[r] + bb, 0.f);
    }
    __syncthreads();

    // Layer 2: RB rows x 2 k-segments x 20 classes = 160 threads, 128-FMA.
    if (t < RB * 2 * NUM_CLASSES) {
        const int r  = t / (2 * NUM_CLASSES);
        const int u  = t - r * 2 * NUM_CLASSES;
        const int j  = u / NUM_CLASSES;
        const int c  = u - j * NUM_CLASSES;
        const int k0 = j * 128;
        float a0 = 0.f, a1 = 0.f;
        for (int k = k0; k < k0 + 128; k += 2) {
            a0 = fmaf(H[r][k],     W2[(k)     * NUM_CLASSES + c], a0);
            a1 = fmaf(H[r][k + 1], W2[(k + 1) * NUM_CLASSES + c], a1);
        }
        part[r][j][c] = a0 + a1;
    }
    __syncthreads();

    if (t < RB * NUM_CLASSES) {
        const int r = t / NUM_CLASSES;
        const int c = t - r * NUM_CLASSES;
        out[(long)(b0 + r) * NUM_CLASSES + c] =
            b2[c] + part[r][0][c] + part[r][1][c];
    }
}

extern "C" void kernel_launch(void* const* d_in, const int* in_sizes, int n_in,
                              void* d_out, int out_size, void* d_ws, size_t ws_size,
                              hipStream_t stream) {
    const int*   x    = (const int*)d_in[0];
    const int*   lens = (const int*)d_in[1];
    const float* emb  = (const float*)d_in[2];
    const float* W1   = (const float*)d_in[3];
    const float* b1   = (const float*)d_in[4];
    const float* W2   = (const float*)d_in[5];
    const float* b2   = (const float*)d_in[6];
    float*       out  = (float*)d_out;

    signed char* qt  = (signed char*)d_ws;                   // 12.8 MB int8 table
    float*       scl = (float*)((char*)d_ws + (16l << 20));  // 400 KB row scales

    // VOCAB*EMB_DIM = 12.8M elems / 4 per thread / 256 per block = 12500 blocks
    convert_q8<<<(VOCAB * EMB_DIM) / (4 * 256), 256, 0, stream>>>(emb, qt, scl);
    fused_kernel<<<B / RB, 256, 0, stream>>>(x, lens, qt, scl, W1, b1, W2, b2, out);
}